// Round 10
// baseline (128.540 us; speedup 1.0000x reference)
//
#include <hip/hip_runtime.h>
#include <math.h>

#define NBATCH 32
#define S      49152
#define NF     24          // frames (2048 samples each)
#define NB     16          // biquads
#define NPAIR  8           // fused filter pairs -> 8 sync rounds
#define NBLK   4           // blocks per batch
#define CHUNK  16          // samples per thread
#define NCH    768         // threads per block
#define NWAVE  12          // waves per block
// 4 blocks per batch; block covers 768*16 = 12288 samples = 6 frames.

__device__ __forceinline__ float clampf(float x, float lo, float hi) {
    return fminf(fmaxf(x, lo), hi);
}

// 16 named scalar signal registers -- guaranteed SSA (no alloca; R1-R4 showed
// the allocator pins VGPR at 84 and spills float arrays regardless of hints).
#define FOREACH_S(OP) \
    OP(s00) OP(s01) OP(s02) OP(s03) OP(s04) OP(s05) OP(s06) OP(s07) \
    OP(s08) OP(s09) OP(s10) OP(s11) OP(s12) OP(s13) OP(s14) OP(s15)

#define DECL_S(x) float x;

// Fused-pair Phase A step (state only). z = (zu,zw, zg,zh) = states of
// filter f then filter f+1; y1 = filter-f output feeds filter f+1.
#define STEPA2(x) { \
    const float y1_ = fmaf(c0f, zu, fmaf(c1f, zw, c2f * (x))); \
    const float nu_ = fmaf(tf00, zu, fmaf(tf01, zw, bf0 * (x))); \
    const float nw_ = fmaf(tf10, zu, fmaf(tf11, zw, bf1 * (x))); \
    const float ng_ = fmaf(tg00, zg, fmaf(tg01, zh, bg0 * y1_)); \
    const float nh_ = fmaf(tg10, zg, fmaf(tg11, zh, bg1 * y1_)); \
    zu = nu_; zw = nw_; zg = ng_; zh = nh_; }

// Fused-pair Phase C step: also emit y2 = pair output, in place.
#define STEPC2(x) { \
    const float y1_ = fmaf(c0f, zu, fmaf(c1f, zw, c2f * (x))); \
    const float y2_ = fmaf(c0g, zg, fmaf(c1g, zh, c2g * y1_)); \
    const float nu_ = fmaf(tf00, zu, fmaf(tf01, zw, bf0 * (x))); \
    const float nw_ = fmaf(tf10, zu, fmaf(tf11, zw, bf1 * (x))); \
    const float ng_ = fmaf(tg00, zg, fmaf(tg01, zh, bg0 * y1_)); \
    const float nh_ = fmaf(tg10, zg, fmaf(tg11, zh, bg1 * y1_)); \
    (x) = y2_; zu = nu_; zw = nw_; zg = ng_; zh = nh_; }

// Square a 4x4 lower block-triangular matrix [A 0; B D] (2x2 blocks):
// A'=A^2, B'=B*A + D*B, D'=D^2.
__device__ __forceinline__ void tri_sq(
    float& a00, float& a01, float& a10, float& a11,
    float& b00, float& b01, float& b10, float& b11,
    float& d00, float& d01, float& d10, float& d11)
{
    const float na00 = a00*a00 + a01*a10;
    const float na01 = a00*a01 + a01*a11;
    const float na10 = a10*a00 + a11*a10;
    const float na11 = a10*a01 + a11*a11;
    const float nb00 = b00*a00 + b01*a10 + d00*b00 + d01*b10;
    const float nb01 = b00*a01 + b01*a11 + d00*b01 + d01*b11;
    const float nb10 = b10*a00 + b11*a10 + d10*b00 + d11*b10;
    const float nb11 = b10*a01 + b11*a11 + d10*b01 + d11*b11;
    const float nd00 = d00*d00 + d01*d10;
    const float nd01 = d00*d01 + d01*d11;
    const float nd10 = d10*d00 + d11*d10;
    const float nd11 = d10*d01 + d11*d11;
    a00=na00; a01=na01; a10=na10; a11=na11;
    b00=nb00; b01=nb01; b10=nb10; b11=nb11;
    d00=nd00; d01=nd01; d10=nd10; d11=nd11;
}

// R9 post-mortem: a fixed ~4us/stage sync cost (barriers + wave0 serial
// publish/poll) survives all per-stage work cuts. R10: fuse 2 cascaded
// filters per scan round (4-dim state, wave-uniform lower-block-tri chunk
// matrix) -> 8 rounds instead of 16. Shfl total unchanged (4/step vs 2, half
// the rounds); barriers/publishes/polls halve. Chunk matrix P^16 and wave
// aggregate P^1024 precomputed per (pair,frame) at init (LDS tables).
// Cross-block protocol unchanged (write-once slots, tag=p+1 != 0xAA poison).
__global__ __launch_bounds__(NCH, 3)
void biquad_chain_kernel(const float* __restrict__ audio,
                         const float* __restrict__ params,
                         float* __restrict__ out,
                         unsigned int* __restrict__ ws)
{
    __shared__ float sfilt[NB][NF][12];  // per-filter: T(4) b(2) c0 c1 c2
    __shared__ float spair[NPAIR][NF][48]; // pair coeffs + M=P^16 + M64=P^1024
    __shared__ float sgain[2][NF];       // [0]=in gain, [1]=out gain
    __shared__ float saggC[NWAVE][4];    // wave aggregate constants
    __shared__ float sv[NWAVE][4];       // per-wave incoming state

    const int t       = threadIdx.x;
    // XCD co-location swizzle (R8): all 4 quarters of a batch land on
    // blockIdx ≡ xcd (mod 8) -> same XCD, L2-local handshake.
    const int xcd     = blockIdx.x & 7;
    const int slot_   = blockIdx.x >> 3;
    const int bt      = xcd * 4 + (slot_ & 3);   // batch
    const int quarter = slot_ >> 2;              // which quarter of the signal
    const int lane    = t & 63;
    const int wave    = t >> 6;
    const int frame   = quarter * 6 + (wave >> 1);  // 2 waves per 2048-frame

    // ------------- init phase 1: per-filter coefficients (t<384) -------------
    if (t < NB * NF) {
        const int f  = t / NF;
        const int fr = t % NF;
        const float* P = params + (size_t)bt * 50 * NF;
        const float fn = P[(3 * f + 0) * NF + fr];
        const float gn = P[(3 * f + 1) * NF + fr];
        const float qn = P[(3 * f + 2) * NF + fr];

        float Q = __expf(-0.69314718f + qn * 3.4657359f);
        Q = clampf(Q, 0.1f, 100.0f);

        float lo, hi;
        int type;                        // 0 hp, 1 lp, 2 peak, 3 lowshelf, 4 highshelf
        if      (f == 0)  { lo = 20.0f;   hi = 500.0f;   type = 0; }
        else if (f == 15) { lo = 5000.0f; hi = 20000.0f; type = 1; }
        else if (f == 1)  { lo = 50.0f;   hi = 16000.0f; type = 3; }
        else if (f == 14) { lo = 50.0f;   hi = 16000.0f; type = 4; }
        else              { lo = 100.0f;  hi = 15000.0f; type = 2; }

        const float fc = __expf(__logf(lo) + fn * (__logf(hi) - __logf(lo)));
        float g_ = __tanf((float)M_PI * fc / 96000.0f);   // angle <= 0.655 rad
        g_ = clampf(g_, 1e-6f, 100.0f);
        const float gdb = -24.0f + 48.0f * gn;

        float a1, a2, a3, m0, m1, m2;
        if (type == 0 || type == 1) {
            const float k = 1.0f / Q;
            a1 = 1.0f / (1.0f + g_ * (g_ + k)); a2 = g_ * a1; a3 = g_ * a2;
            if (type == 0) { m0 = 1.0f; m1 = -k;   m2 = -1.0f; }
            else           { m0 = 0.0f; m1 = 0.0f; m2 = 1.0f;  }
        } else if (type == 2) {
            const float A = __expf(gdb * (2.30258509f / 40.0f));
            const float k = (gdb >= 0.0f) ? 1.0f / (Q * A) : A / Q;
            a1 = 1.0f / (1.0f + g_ * (g_ + k)); a2 = g_ * a1; a3 = g_ * a2;
            m0 = 1.0f; m1 = k * (A * A - 1.0f); m2 = 0.0f;
        } else {
            const float A  = __expf(gdb * (2.30258509f / 40.0f));
            const float sA = sqrtf(A);
            const float k  = 1.0f / Q;
            float gs;
            if (type == 3) gs = (gdb >= 0.0f) ? g_ / sA : g_ * sA;
            else           gs = (gdb >= 0.0f) ? g_ * sA : g_ / sA;
            a1 = 1.0f / (1.0f + gs * (gs + k)); a2 = gs * a1; a3 = gs * a2;
            if (type == 3) { m0 = 1.0f;  m1 = k * (A - 1.0f);      m2 = A * A - 1.0f; }
            else           { m0 = A * A; m1 = k * (1.0f - A) * A;  m2 = 1.0f - A * A; }
        }

        const float q2  = a2 * a2 + a3;
        sfilt[f][fr][0] = 2.0f * a1 - 1.0f;            // t00
        sfilt[f][fr][1] = -2.0f * a2;                  // t01
        sfilt[f][fr][2] = 2.0f * a1 * a2;              // t10
        sfilt[f][fr][3] = 1.0f - 2.0f * q2;            // t11
        sfilt[f][fr][4] = 2.0f * a2;                   // b0
        sfilt[f][fr][5] = 2.0f * q2;                   // b1
        sfilt[f][fr][6] = a1 * (m1 + m2 * a2);         // c0
        sfilt[f][fr][7] = m2 * (1.0f - q2) - m1 * a2;  // c1
        sfilt[f][fr][8] = m0 + m1 * a2 + m2 * q2;      // c2
    }
    if (t >= 384 && t < 384 + 2 * NF) {
        const int idx = t - 384;
        const int which = idx / NF;
        const int fr    = idx % NF;
        const float* P = params + (size_t)bt * 50 * NF;
        const float p  = P[(48 + which) * NF + fr];
        const float db = -60.0f + 60.0f * p;
        sgain[which][fr] = __expf(db * (2.30258509f / 20.0f));
    }
    __syncthreads();

    // ------------- init phase 2: pair tables (t<192) -------------
    if (t < NPAIR * NF) {
        const int p  = t / NF;
        const int fr = t % NF;
        const float* F0 = sfilt[2 * p][fr];
        const float* F1 = sfilt[2 * p + 1][fr];
        float* W = spair[p][fr];
        // layout: [0..3]=Tf [4..7]=bf0,bf1,c0f,c1f [8..11]=c2f,tg00,tg01,tg10
        //         [12..15]=tg11,bg0,bg1,c0g [16..19]=c1g,c2g,0,0
        //         [20..31]=M (A,B,D) [32..43]=M64 (A,B,D)
        W[0]=F0[0]; W[1]=F0[1]; W[2]=F0[2]; W[3]=F0[3];
        W[4]=F0[4]; W[5]=F0[5]; W[6]=F0[6]; W[7]=F0[7];
        W[8]=F0[8]; W[9]=F1[0]; W[10]=F1[1]; W[11]=F1[2];
        W[12]=F1[3]; W[13]=F1[4]; W[14]=F1[5]; W[15]=F1[6];
        W[16]=F1[7]; W[17]=F1[8]; W[18]=0.0f; W[19]=0.0f;

        // per-sample pair matrix P = [Tf 0; bg⊗cf Tg]
        float a00=F0[0], a01=F0[1], a10=F0[2], a11=F0[3];
        float b00=F1[4]*F0[6], b01=F1[4]*F0[7];
        float b10=F1[5]*F0[6], b11=F1[5]*F0[7];
        float d00=F1[0], d01=F1[1], d10=F1[2], d11=F1[3];
        #pragma unroll
        for (int i = 0; i < 4; i++)   // P^16
            tri_sq(a00,a01,a10,a11,b00,b01,b10,b11,d00,d01,d10,d11);
        W[20]=a00; W[21]=a01; W[22]=a10; W[23]=a11;
        W[24]=b00; W[25]=b01; W[26]=b10; W[27]=b11;
        W[28]=d00; W[29]=d01; W[30]=d10; W[31]=d11;
        #pragma unroll
        for (int i = 0; i < 6; i++)   // (P^16)^64 = P^1024 wave aggregate
            tri_sq(a00,a01,a10,a11,b00,b01,b10,b11,d00,d01,d10,d11);
        W[32]=a00; W[33]=a01; W[34]=a10; W[35]=a11;
        W[36]=b00; W[37]=b01; W[38]=b10; W[39]=b11;
        W[40]=d00; W[41]=d01; W[42]=d10; W[43]=d11;
    }
    __syncthreads();

    // ---------------- load chunk (with input gain) ----------------
    FOREACH_S(DECL_S)
    {
        const float ing = sgain[0][frame];
        const float* base = audio + (size_t)bt * S
                          + (size_t)(quarter * NCH + t) * CHUNK;
        float4 q;
        q = *(const float4*)(base +  0); s00 = q.x*ing; s01 = q.y*ing; s02 = q.z*ing; s03 = q.w*ing;
        q = *(const float4*)(base +  4); s04 = q.x*ing; s05 = q.y*ing; s06 = q.z*ing; s07 = q.w*ing;
        q = *(const float4*)(base +  8); s08 = q.x*ing; s09 = q.y*ing; s10 = q.z*ing; s11 = q.w*ing;
        q = *(const float4*)(base + 12); s12 = q.x*ing; s13 = q.y*ing; s14 = q.z*ing; s15 = q.w*ing;
    }

    // ---------------- 8 fused pair rounds ----------------
    #pragma unroll 1
    for (int p = 0; p < NPAIR; p++) {
        const float* W = spair[p][frame];
        const float4 q0 = *(const float4*)&W[0];
        const float4 q1 = *(const float4*)&W[4];
        const float4 q2 = *(const float4*)&W[8];
        const float4 q3 = *(const float4*)&W[12];
        const float4 q4 = *(const float4*)&W[16];
        const float tf00=q0.x, tf01=q0.y, tf10=q0.z, tf11=q0.w;
        const float bf0=q1.x, bf1=q1.y, c0f=q1.z, c1f=q1.w;
        const float c2f=q2.x, tg00=q2.y, tg01=q2.z, tg10=q2.w;
        const float tg11=q3.x, bg0=q3.y, bg1=q3.z, c0g=q3.w;
        const float c1g=q4.x, c2g=q4.y;

        // Phase A: zero-state run over own chunk -> affine constant (4-dim)
        float zu = 0.0f, zw = 0.0f, zg = 0.0f, zh = 0.0f;
        FOREACH_S(STEPA2)
        float cx0 = zu, cx1 = zw, cx2 = zg, cx3 = zh;

        // constants-only Kogge-Stone with wave-uniform tri matrix M = P^16
        float ma00, ma01, ma10, ma11, mb00, mb01, mb10, mb11, md00, md01, md10, md11;
        {
            const float4 m0v = *(const float4*)&W[20];
            const float4 m1v = *(const float4*)&W[24];
            const float4 m2v = *(const float4*)&W[28];
            ma00=m0v.x; ma01=m0v.y; ma10=m0v.z; ma11=m0v.w;
            mb00=m1v.x; mb01=m1v.y; mb10=m1v.z; mb11=m1v.w;
            md00=m2v.x; md01=m2v.y; md10=m2v.z; md11=m2v.w;
        }
        #pragma unroll
        for (int d = 1; d < 64; d <<= 1) {
            const float l0 = __shfl_up(cx0, d);
            const float l1 = __shfl_up(cx1, d);
            const float l2 = __shfl_up(cx2, d);
            const float l3 = __shfl_up(cx3, d);
            if (lane >= d) {
                cx0 = fmaf(ma00, l0, fmaf(ma01, l1, cx0));
                cx1 = fmaf(ma10, l0, fmaf(ma11, l1, cx1));
                cx2 = fmaf(mb00, l0, fmaf(mb01, l1, fmaf(md00, l2, fmaf(md01, l3, cx2))));
                cx3 = fmaf(mb10, l0, fmaf(mb11, l1, fmaf(md10, l2, fmaf(md11, l3, cx3))));
            }
            if (d < 32)
                tri_sq(ma00,ma01,ma10,ma11,mb00,mb01,mb10,mb11,md00,md01,md10,md11);
        }

        if (lane == 63) {
            *(float4*)saggC[wave] = make_float4(cx0, cx1, cx2, cx3);
        }
        __syncthreads();

        const unsigned int tag = (unsigned int)(p + 1);
        unsigned int* stagebase = ws + (((bt * NPAIR + p) * NBLK)) * 20;

        // wave0: second-level tri-affine scan over 12 wave aggregates,
        // publish block aggregate, poll predecessors, distribute v per wave.
        if (wave == 0) {
            float Ga00=1.0f,Ga01=0.0f,Ga10=0.0f,Ga11=1.0f;
            float Gb00=0.0f,Gb01=0.0f,Gb10=0.0f,Gb11=0.0f;
            float Gd00=1.0f,Gd01=0.0f,Gd10=0.0f,Gd11=1.0f;
            float Gc0=0.0f,Gc1=0.0f,Gc2=0.0f,Gc3=0.0f;
            if (lane < NWAVE) {
                const float* WM = spair[p][quarter * 6 + (lane >> 1)];
                const float4 m0v = *(const float4*)&WM[32];
                const float4 m1v = *(const float4*)&WM[36];
                const float4 m2v = *(const float4*)&WM[40];
                Ga00=m0v.x; Ga01=m0v.y; Ga10=m0v.z; Ga11=m0v.w;
                Gb00=m1v.x; Gb01=m1v.y; Gb10=m1v.z; Gb11=m1v.w;
                Gd00=m2v.x; Gd01=m2v.y; Gd10=m2v.z; Gd11=m2v.w;
                const float4 cv = *(const float4*)saggC[lane];
                Gc0=cv.x; Gc1=cv.y; Gc2=cv.z; Gc3=cv.w;
            }
            #pragma unroll
            for (int d = 1; d < 16; d <<= 1) {
                const float la00=__shfl_up(Ga00,d), la01=__shfl_up(Ga01,d);
                const float la10=__shfl_up(Ga10,d), la11=__shfl_up(Ga11,d);
                const float lb00=__shfl_up(Gb00,d), lb01=__shfl_up(Gb01,d);
                const float lb10=__shfl_up(Gb10,d), lb11=__shfl_up(Gb11,d);
                const float ld00=__shfl_up(Gd00,d), ld01=__shfl_up(Gd01,d);
                const float ld10=__shfl_up(Gd10,d), ld11=__shfl_up(Gd11,d);
                const float lc0=__shfl_up(Gc0,d), lc1=__shfl_up(Gc1,d);
                const float lc2=__shfl_up(Gc2,d), lc3=__shfl_up(Gc3,d);
                if (lane >= d && lane < NWAVE) {
                    // compose self ∘ left
                    const float na00 = Ga00*la00 + Ga01*la10;
                    const float na01 = Ga00*la01 + Ga01*la11;
                    const float na10 = Ga10*la00 + Ga11*la10;
                    const float na11 = Ga10*la01 + Ga11*la11;
                    const float nb00 = Gb00*la00 + Gb01*la10 + Gd00*lb00 + Gd01*lb10;
                    const float nb01 = Gb00*la01 + Gb01*la11 + Gd00*lb01 + Gd01*lb11;
                    const float nb10 = Gb10*la00 + Gb11*la10 + Gd10*lb00 + Gd11*lb10;
                    const float nb11 = Gb10*la01 + Gb11*la11 + Gd10*lb01 + Gd11*lb11;
                    const float nd00 = Gd00*ld00 + Gd01*ld10;
                    const float nd01 = Gd00*ld01 + Gd01*ld11;
                    const float nd10 = Gd10*ld00 + Gd11*ld10;
                    const float nd11 = Gd10*ld01 + Gd11*ld11;
                    const float nc0 = Ga00*lc0 + Ga01*lc1 + Gc0;
                    const float nc1 = Ga10*lc0 + Ga11*lc1 + Gc1;
                    const float nc2 = Gb00*lc0 + Gb01*lc1 + Gd00*lc2 + Gd01*lc3 + Gc2;
                    const float nc3 = Gb10*lc0 + Gb11*lc1 + Gd10*lc2 + Gd11*lc3 + Gc3;
                    Ga00=na00; Ga01=na01; Ga10=na10; Ga11=na11;
                    Gb00=nb00; Gb01=nb01; Gb10=nb10; Gb11=nb11;
                    Gd00=nd00; Gd01=nd01; Gd10=nd10; Gd11=nd11;
                    Gc0=nc0; Gc1=nc1; Gc2=nc2; Gc3=nc3;
                }
            }

            // publish block aggregate (inclusive at lane 11)
            if (quarter < NBLK - 1 && lane == NWAVE - 1) {
                unsigned int* slot = stagebase + quarter * 20;
                float* dp = (float*)(slot + 1);
                __hip_atomic_store(&dp[0],  Ga00, __ATOMIC_RELAXED, __HIP_MEMORY_SCOPE_AGENT);
                __hip_atomic_store(&dp[1],  Ga01, __ATOMIC_RELAXED, __HIP_MEMORY_SCOPE_AGENT);
                __hip_atomic_store(&dp[2],  Ga10, __ATOMIC_RELAXED, __HIP_MEMORY_SCOPE_AGENT);
                __hip_atomic_store(&dp[3],  Ga11, __ATOMIC_RELAXED, __HIP_MEMORY_SCOPE_AGENT);
                __hip_atomic_store(&dp[4],  Gb00, __ATOMIC_RELAXED, __HIP_MEMORY_SCOPE_AGENT);
                __hip_atomic_store(&dp[5],  Gb01, __ATOMIC_RELAXED, __HIP_MEMORY_SCOPE_AGENT);
                __hip_atomic_store(&dp[6],  Gb10, __ATOMIC_RELAXED, __HIP_MEMORY_SCOPE_AGENT);
                __hip_atomic_store(&dp[7],  Gb11, __ATOMIC_RELAXED, __HIP_MEMORY_SCOPE_AGENT);
                __hip_atomic_store(&dp[8],  Gd00, __ATOMIC_RELAXED, __HIP_MEMORY_SCOPE_AGENT);
                __hip_atomic_store(&dp[9],  Gd01, __ATOMIC_RELAXED, __HIP_MEMORY_SCOPE_AGENT);
                __hip_atomic_store(&dp[10], Gd10, __ATOMIC_RELAXED, __HIP_MEMORY_SCOPE_AGENT);
                __hip_atomic_store(&dp[11], Gd11, __ATOMIC_RELAXED, __HIP_MEMORY_SCOPE_AGENT);
                __hip_atomic_store(&dp[12], Gc0,  __ATOMIC_RELAXED, __HIP_MEMORY_SCOPE_AGENT);
                __hip_atomic_store(&dp[13], Gc1,  __ATOMIC_RELAXED, __HIP_MEMORY_SCOPE_AGENT);
                __hip_atomic_store(&dp[14], Gc2,  __ATOMIC_RELAXED, __HIP_MEMORY_SCOPE_AGENT);
                __hip_atomic_store(&dp[15], Gc3,  __ATOMIC_RELAXED, __HIP_MEMORY_SCOPE_AGENT);
                __hip_atomic_store(slot, tag, __ATOMIC_RELEASE, __HIP_MEMORY_SCOPE_AGENT);
            }

            // exclusive wave prefix
            float Pa00=__shfl_up(Ga00,1), Pa01=__shfl_up(Ga01,1);
            float Pa10=__shfl_up(Ga10,1), Pa11=__shfl_up(Ga11,1);
            float Pb00=__shfl_up(Gb00,1), Pb01=__shfl_up(Gb01,1);
            float Pb10=__shfl_up(Gb10,1), Pb11=__shfl_up(Gb11,1);
            float Pd00=__shfl_up(Gd00,1), Pd01=__shfl_up(Gd01,1);
            float Pd10=__shfl_up(Gd10,1), Pd11=__shfl_up(Gd11,1);
            float Pc0=__shfl_up(Gc0,1), Pc1=__shfl_up(Gc1,1);
            float Pc2=__shfl_up(Gc2,1), Pc3=__shfl_up(Gc3,1);
            if (lane == 0) {
                Pa00=1.0f; Pa01=0.0f; Pa10=0.0f; Pa11=1.0f;
                Pb00=0.0f; Pb01=0.0f; Pb10=0.0f; Pb11=0.0f;
                Pd00=1.0f; Pd01=0.0f; Pd10=0.0f; Pd11=1.0f;
                Pc0=0.0f; Pc1=0.0f; Pc2=0.0f; Pc3=0.0f;
            }

            // lane 0: poll predecessor blocks, fold block incoming state S0
            float S0a=0.0f, S0b=0.0f, S0c=0.0f, S0d=0.0f;
            if (lane == 0 && quarter > 0) {
                float sx0=0.0f, sx1=0.0f, sx2=0.0f, sx3=0.0f;
                for (int k2 = 0; k2 < quarter; k2++) {
                    unsigned int* slot = stagebase + k2 * 20;
                    while (__hip_atomic_load(slot, __ATOMIC_ACQUIRE, __HIP_MEMORY_SCOPE_AGENT) != tag) {
                        __builtin_amdgcn_s_sleep(1);
                    }
                    float* dp = (float*)(slot + 1);
                    float m[16];
                    #pragma unroll
                    for (int i = 0; i < 16; i++)
                        m[i] = __hip_atomic_load(&dp[i], __ATOMIC_RELAXED, __HIP_MEMORY_SCOPE_AGENT);
                    const float n0 = m[0]*sx0 + m[1]*sx1 + m[12];
                    const float n1 = m[2]*sx0 + m[3]*sx1 + m[13];
                    const float n2 = m[4]*sx0 + m[5]*sx1 + m[8]*sx2 + m[9]*sx3 + m[14];
                    const float n3 = m[6]*sx0 + m[7]*sx1 + m[10]*sx2 + m[11]*sx3 + m[15];
                    sx0=n0; sx1=n1; sx2=n2; sx3=n3;
                }
                S0a=sx0; S0b=sx1; S0c=sx2; S0d=sx3;
            }
            S0a = __shfl(S0a, 0); S0b = __shfl(S0b, 0);
            S0c = __shfl(S0c, 0); S0d = __shfl(S0d, 0);

            // per-wave incoming state v = P(S0); lanes 0..11 write to LDS
            if (lane < NWAVE) {
                const float v0 = Pa00*S0a + Pa01*S0b + Pc0;
                const float v1 = Pa10*S0a + Pa11*S0b + Pc1;
                const float v2 = Pb00*S0a + Pb01*S0b + Pd00*S0c + Pd01*S0d + Pc2;
                const float v3 = Pb10*S0a + Pb11*S0b + Pd10*S0c + Pd11*S0d + Pc3;
                *(float4*)sv[lane] = make_float4(v0, v1, v2, v3);
            }
        }
        __syncthreads();

        const float4 vv = *(const float4*)sv[wave];

        // lane-exclusive constants
        float ce0 = __shfl_up(cx0, 1);
        float ce1 = __shfl_up(cx1, 1);
        float ce2 = __shfl_up(cx2, 1);
        float ce3 = __shfl_up(cx3, 1);
        if (lane == 0) { ce0 = 0.0f; ce1 = 0.0f; ce2 = 0.0f; ce3 = 0.0f; }

        // w = M^lane * v via in-register binary exponentiation (reload M)
        float w0 = vv.x, w1 = vv.y, w2 = vv.z, w3 = vv.w;
        {
            const float4 m0v = *(const float4*)&W[20];
            const float4 m1v = *(const float4*)&W[24];
            const float4 m2v = *(const float4*)&W[28];
            float pa00=m0v.x, pa01=m0v.y, pa10=m0v.z, pa11=m0v.w;
            float pb00=m1v.x, pb01=m1v.y, pb10=m1v.z, pb11=m1v.w;
            float pd00=m2v.x, pd01=m2v.y, pd10=m2v.z, pd11=m2v.w;
            #pragma unroll
            for (int b = 0; b < 6; b++) {
                if (lane & (1 << b)) {
                    const float n0 = pa00*w0 + pa01*w1;
                    const float n1 = pa10*w0 + pa11*w1;
                    const float n2 = pb00*w0 + pb01*w1 + pd00*w2 + pd01*w3;
                    const float n3 = pb10*w0 + pb11*w1 + pd10*w2 + pd11*w3;
                    w0=n0; w1=n1; w2=n2; w3=n3;
                }
                if (b < 5)
                    tri_sq(pa00,pa01,pa10,pa11,pb00,pb01,pb10,pb11,pd00,pd01,pd10,pd11);
            }
        }
        zu = w0 + ce0;
        zw = w1 + ce1;
        zg = w2 + ce2;
        zh = w3 + ce3;

        // Phase C: true run from incoming state, write outputs in place
        FOREACH_S(STEPC2)
    }

    // ---------------- store (with output gain) ----------------
    {
        const float og = sgain[1][frame];
        float* base = out + (size_t)bt * S + (size_t)(quarter * NCH + t) * CHUNK;
        float4 q;
        q.x = s00*og; q.y = s01*og; q.z = s02*og; q.w = s03*og; *(float4*)(base +  0) = q;
        q.x = s04*og; q.y = s05*og; q.z = s06*og; q.w = s07*og; *(float4*)(base +  4) = q;
        q.x = s08*og; q.y = s09*og; q.z = s10*og; q.w = s11*og; *(float4*)(base +  8) = q;
        q.x = s12*og; q.y = s13*og; q.z = s14*og; q.w = s15*og; *(float4*)(base + 12) = q;
    }
}

extern "C" void kernel_launch(void* const* d_in, const int* in_sizes, int n_in,
                              void* d_out, int out_size, void* d_ws, size_t ws_size,
                              hipStream_t stream)
{
    const float* audio  = (const float*)d_in[0];
    const float* params = (const float*)d_in[1];
    float* out = (float*)d_out;
    unsigned int* ws = (unsigned int*)d_ws;
    biquad_chain_kernel<<<NBLK * NBATCH, NCH, 0, stream>>>(audio, params, out, ws);
}